// Round 13
// baseline (266.143 us; speedup 1.0000x reference)
//
#include <hip/hip_runtime.h>

#define N_NODES 50000
#define N_EDGES 800000
#define IN_C 128
#define MSG_C 64
#define OUT_C 128
#define SCAN_NB 49   // ceil(50000/1024)

typedef __attribute__((ext_vector_type(8))) short short8v;  // 8 bf16 (4 VGPRs)
typedef __attribute__((ext_vector_type(4))) float f32x4;
typedef __attribute__((ext_vector_type(2))) unsigned int u32x2;
typedef __attribute__((ext_vector_type(4))) unsigned int u32x4;

__device__ __forceinline__ unsigned short f2bf(float f) {
    union { float f; unsigned int u; } v; v.f = f;
    unsigned int r = (v.u + 0x7FFFu + ((v.u >> 16) & 1u)) >> 16;
    return (unsigned short)r;
}
__device__ __forceinline__ float bflo(unsigned u) {
    union { unsigned u; float f; } v; v.u = u << 16; return v.f;
}
__device__ __forceinline__ float bfhi(unsigned u) {
    union { unsigned u; float f; } v; v.u = u & 0xFFFF0000u; return v.f;
}

// ---------------------------------------------------------------------------
// init: zero deg (12500 int4) + transpose/convert weights to bf16 Wt[n][k]
// ---------------------------------------------------------------------------
__global__ __launch_bounds__(256) void init_kernel(
    int4* __restrict__ deg4,
    const float* __restrict__ W1, const float* __restrict__ W2,
    const float* __restrict__ W3, unsigned short* __restrict__ Wt1,
    unsigned short* __restrict__ Wt2, unsigned short* __restrict__ Wt3)
{
    int idx = blockIdx.x * 256 + threadIdx.x;
    if (idx < 12500) deg4[idx] = make_int4(0, 0, 0, 0);
    if (idx < 24576) {
        int k = idx >> 7, n = idx & 127;
        Wt1[n * 192 + k] = f2bf(W1[idx]);
    } else if (idx < 40960) {
        int t = idx - 24576;
        int k = t >> 7, n = t & 127;
        Wt2[n * 128 + k] = f2bf(W2[t]);
    } else if (idx < 57344) {
        int t = idx - 40960;
        int k = t >> 7, n = t & 127;
        Wt3[n * 128 + k] = f2bf(W3[t]);
    }
}

// ---------------------------------------------------------------------------
// CSR offsets: histogram -> scan_a -> scan_bc (seeds cursor)
// ---------------------------------------------------------------------------
__global__ __launch_bounds__(256) void hist_kernel(const int* __restrict__ edge_index,
                                                   int* __restrict__ deg)
{
    int i = blockIdx.x * 256 + threadIdx.x;
    if (i >= N_EDGES / 4) return;
    int4 d4 = *reinterpret_cast<const int4*>(edge_index + N_EDGES + i * 4);
    atomicAdd(&deg[d4.x], 1);
    atomicAdd(&deg[d4.y], 1);
    atomicAdd(&deg[d4.z], 1);
    atomicAdd(&deg[d4.w], 1);
}

__global__ __launch_bounds__(1024) void scan_a_kernel(const int* __restrict__ deg,
                                                      int* __restrict__ offsets,
                                                      int* __restrict__ bsum)
{
    __shared__ int wsum[16];
    const int tid = threadIdx.x, lane = tid & 63, wid = tid >> 6;
    int i = blockIdx.x * 1024 + tid;
    int v = (i < N_NODES) ? deg[i] : 0;
    int s = v;
    #pragma unroll
    for (int d = 1; d < 64; d <<= 1) {
        int t = __shfl_up(s, d);
        if (lane >= d) s += t;
    }
    if (lane == 63) wsum[wid] = s;
    __syncthreads();
    if (wid == 0 && lane < 16) {
        int ws = wsum[lane];
        int ss = ws;
        #pragma unroll
        for (int d = 1; d < 16; d <<= 1) {
            int t = __shfl_up(ss, d);
            if (lane >= d) ss += t;
        }
        wsum[lane] = ss - ws;   // exclusive wave offset
    }
    __syncthreads();
    if (i < N_NODES) offsets[i] = s - v + wsum[wid];
    if (tid == 1023) bsum[blockIdx.x] = wsum[15] + s;
}

// every block redundantly scans the 49 block sums; finalizes offsets + cursor
__global__ __launch_bounds__(1024) void scan_bc_kernel(int* __restrict__ offsets,
                                                       int* __restrict__ cursor,
                                                       const int* __restrict__ bsum)
{
    __shared__ int bpre_s, btot_s;
    const int tid = threadIdx.x;
    if (tid < 64) {
        int v = (tid < SCAN_NB) ? bsum[tid] : 0;
        int s = v;
        #pragma unroll
        for (int d = 1; d < 64; d <<= 1) {
            int t = __shfl_up(s, d);
            if (tid >= d) s += t;
        }
        if (tid == (int)blockIdx.x) bpre_s = s - v;   // exclusive prefix of my block
        if (tid == SCAN_NB - 1) btot_s = s;           // grand total
    }
    __syncthreads();
    int i = blockIdx.x * 1024 + tid;
    if (i < N_NODES) {
        int o = offsets[i] + bpre_s;
        offsets[i] = o;
        cursor[i] = o;
    }
    if (blockIdx.x == 0 && tid == 0) offsets[N_NODES] = btot_s;  // == N_EDGES
}

// ---------------------------------------------------------------------------
// permute: stream messages in order (coalesced 256 B reads), convert to bf16,
// write each row to its CSR slot as ONE aligned 128 B full-line write.
// ---------------------------------------------------------------------------
__global__ __launch_bounds__(256) void permute_kernel(
    const int* __restrict__ edge_index, const float* __restrict__ message,
    int* __restrict__ cursor, unsigned int* __restrict__ pbuf)
{
    int t = blockIdx.x * 256 + threadIdx.x;
    int e = t >> 4;
    if (e >= N_EDGES) return;
    int lane = threadIdx.x & 63;
    int s = lane & 15;
    int dest = edge_index[N_EDGES + e];
    int pos = 0;
    if (s == 0) pos = atomicAdd(&cursor[dest], 1);
    pos = __shfl(pos, lane & 48);          // broadcast within the 16-lane group
    f32x4 v = __builtin_nontemporal_load(
        reinterpret_cast<const f32x4*>(message + (long)e * MSG_C + s * 4));
    u32x2 p;
    p.x = (unsigned)f2bf(v.x) | ((unsigned)f2bf(v.y) << 16);
    p.y = (unsigned)f2bf(v.z) | ((unsigned)f2bf(v.w) << 16);
    __builtin_nontemporal_store(p,
        reinterpret_cast<u32x2*>(pbuf + (long)pos * 32 + s * 2));
}

// ---------------------------------------------------------------------------
// MFMA MLP + LayerNorm with FUSED segsum prologue: each wave computes its 16
// nodes' message sums directly from pbuf (contiguous CSR rows, streaming
// u32x4 loads) into sA0[:,128:192]. Removes the segsum kernel + aggr buffer.
// Weights staged in LDS, double-buffered 64-k chunks; 79.9 KB LDS -> 2 blk/CU.
// A-frag: row = lane&15, k = (lane>>4)*8 + j ; C/D: col = lane&15,
// row = (lane>>4)*4 + j  [m89-verified]
// ---------------------------------------------------------------------------
__device__ __forceinline__ void stage_load(const unsigned short* __restrict__ Wt,
                                           int KW, int k0, int tid, u32x4 r[4])
{
    const u32x4* src = reinterpret_cast<const u32x4*>(
        Wt + (size_t)(tid >> 1) * KW + k0 + (tid & 1) * 32);
    r[0] = src[0]; r[1] = src[1]; r[2] = src[2]; r[3] = src[3];
}

__device__ __forceinline__ void stage_write(unsigned short* __restrict__ sw,
                                            int tid, const u32x4 r[4])
{
    u32x4* dst = reinterpret_cast<u32x4*>(sw + (tid >> 1) * 72 + (tid & 1) * 32);
    dst[0] = r[0]; dst[1] = r[1]; dst[2] = r[2]; dst[3] = r[3];
}

template<int KW, bool BIAS>
__device__ __forceinline__ void gemm_layer_lds(
    const unsigned short* __restrict__ Wt, const float* __restrict__ bias,
    unsigned short* __restrict__ sW,      // [2][128][72] flat
    const short8v* af, int tid, int lr, int lg, f32x4 acc[8])
{
    constexpr int NCH = KW / 64;
    #pragma unroll
    for (int ct = 0; ct < 8; ++ct) {
        float bv = BIAS ? bias[ct * 16 + lr] : 0.f;
        acc[ct] = (f32x4){bv, bv, bv, bv};
    }
    u32x4 r[4];
    stage_load(Wt, KW, 0, tid, r);
    stage_write(sW, tid, r);
    __syncthreads();
    #pragma unroll
    for (int c = 0; c < NCH; ++c) {
        if (c + 1 < NCH) stage_load(Wt, KW, (c + 1) * 64, tid, r);   // issue early
        const unsigned short* swc = sW + (c & 1) * (128 * 72);
        #pragma unroll
        for (int k2 = 0; k2 < 2; ++k2) {
            #pragma unroll
            for (int ct = 0; ct < 8; ++ct) {
                short8v b = *reinterpret_cast<const short8v*>(
                    swc + (ct * 16 + lr) * 72 + k2 * 32 + lg * 8);
                acc[ct] = __builtin_amdgcn_mfma_f32_16x16x32_bf16(
                    af[c * 2 + k2], b, acc[ct], 0, 0, 0);
            }
        }
        if (c + 1 < NCH) stage_write(sW + ((c + 1) & 1) * (128 * 72), tid, r);
        __syncthreads();
    }
}

__device__ __forceinline__ void store_h_leaky(unsigned short* __restrict__ H,
                                              int lr, int lg, const f32x4 acc[8])
{
    #pragma unroll
    for (int ct = 0; ct < 8; ++ct)
        #pragma unroll
        for (int j = 0; j < 4; ++j) {
            float v = acc[ct][j];
            v = v > 0.f ? v : 0.2f * v;
            H[(lg * 4 + j) * 136 + ct * 16 + lr] = f2bf(v);
        }
}

__global__ __launch_bounds__(256, 2) void mlp_mfma_kernel(
    const float* __restrict__ x, const int* __restrict__ offsets,
    const u32x4* __restrict__ pbuf4,
    const unsigned short* __restrict__ Wt1, const float* __restrict__ b1,
    const unsigned short* __restrict__ Wt2, const float* __restrict__ b2,
    const unsigned short* __restrict__ Wt3, const float* __restrict__ gamma,
    const float* __restrict__ beta, float* __restrict__ out)
{
    __shared__ __align__(16) unsigned short sA0[4][16][200];  // 25600 B
    __shared__ __align__(16) unsigned short sH[4][16][136];   // 17408 B
    __shared__ __align__(16) unsigned short sW[2 * 128 * 72]; // 36864 B
    // total 79,872 B -> 2 blocks/CU

    const int tid = threadIdx.x;
    const int w = tid >> 6, l = tid & 63;
    const int lr = l & 15, lg = l >> 4;
    const int R0 = blockIdx.x * 64 + w * 16;
    const bool act = (R0 < N_NODES);   // inactive waves still hit all barriers

    // ---- stage x (f32 -> bf16) into sA0[:, 0:128]
    #pragma unroll
    for (int i = 0; i < 4; ++i) {
        int r = lg + i * 4;
        int c0 = lr * 8;
        int gr = R0 + r;
        float4 v0 = {}, v1 = {};
        if (gr < N_NODES) {
            const float4* xp = reinterpret_cast<const float4*>(x + (size_t)gr * IN_C + c0);
            v0 = xp[0]; v1 = xp[1];
        }
        uint4 p;
        p.x = (unsigned)f2bf(v0.x) | ((unsigned)f2bf(v0.y) << 16);
        p.y = (unsigned)f2bf(v0.z) | ((unsigned)f2bf(v0.w) << 16);
        p.z = (unsigned)f2bf(v1.x) | ((unsigned)f2bf(v1.y) << 16);
        p.w = (unsigned)f2bf(v1.z) | ((unsigned)f2bf(v1.w) << 16);
        *reinterpret_cast<uint4*>(&sA0[w][r][c0]) = p;
    }

    // ---- FUSED segsum: pbuf rows (contiguous per node) -> sA0[:, 128:192]
    if (act) {
        #pragma unroll 1
        for (int m = 0; m < 16; ++m) {
            int n = R0 + m;
            int s0 = offsets[n], e0 = offsets[n + 1];
            long base = (long)s0 * 8;            // u32x4 units (row = 8 units)
            int cntel = (e0 - s0) * 8;
            float a0 = 0.f, a1 = 0.f, a2 = 0.f, a3 = 0.f,
                  a4 = 0.f, a5 = 0.f, a6 = 0.f, a7 = 0.f;
            for (int k = l; k < cntel; k += 64) {
                u32x4 u = __builtin_nontemporal_load(pbuf4 + base + k);
                a0 += bflo(u.x); a1 += bfhi(u.x);
                a2 += bflo(u.y); a3 += bfhi(u.y);
                a4 += bflo(u.z); a5 += bfhi(u.z);
                a6 += bflo(u.w); a7 += bfhi(u.w);
            }
            #pragma unroll
            for (int mm = 8; mm <= 32; mm <<= 1) {
                a0 += __shfl_xor(a0, mm); a1 += __shfl_xor(a1, mm);
                a2 += __shfl_xor(a2, mm); a3 += __shfl_xor(a3, mm);
                a4 += __shfl_xor(a4, mm); a5 += __shfl_xor(a5, mm);
                a6 += __shfl_xor(a6, mm); a7 += __shfl_xor(a7, mm);
            }
            if (l < 8) {                         // lane l holds channels l*8..l*8+7
                uint4 p;
                p.x = (unsigned)f2bf(a0) | ((unsigned)f2bf(a1) << 16);
                p.y = (unsigned)f2bf(a2) | ((unsigned)f2bf(a3) << 16);
                p.z = (unsigned)f2bf(a4) | ((unsigned)f2bf(a5) << 16);
                p.w = (unsigned)f2bf(a6) | ((unsigned)f2bf(a7) << 16);
                *reinterpret_cast<uint4*>(&sA0[w][m][IN_C + l * 8]) = p;
            }
        }
    } else if (l < 8) {
        uint4 z = {};
        #pragma unroll
        for (int m = 0; m < 16; ++m)
            *reinterpret_cast<uint4*>(&sA0[w][m][IN_C + l * 8]) = z;
    }

    f32x4 acc[8];
    short8v af[6];

    // layer 1: K=192
    #pragma unroll
    for (int ks = 0; ks < 6; ++ks)
        af[ks] = *reinterpret_cast<const short8v*>(&sA0[w][lr][ks * 32 + lg * 8]);
    gemm_layer_lds<192, true>(Wt1, b1, sW, af, tid, lr, lg, acc);
    store_h_leaky(&sH[w][0][0], lr, lg, acc);

    // layer 2: K=128
    #pragma unroll
    for (int ks = 0; ks < 4; ++ks)
        af[ks] = *reinterpret_cast<const short8v*>(&sH[w][lr][ks * 32 + lg * 8]);
    gemm_layer_lds<128, true>(Wt2, b2, sW, af, tid, lr, lg, acc);
    store_h_leaky(&sH[w][0][0], lr, lg, acc);   // h2 overwrites h1 (a-frags in regs)

    // layer 3: K=128, no bias
    #pragma unroll
    for (int ks = 0; ks < 4; ++ks)
        af[ks] = *reinterpret_cast<const short8v*>(&sH[w][lr][ks * 32 + lg * 8]);
    gemm_layer_lds<128, false>(Wt3, nullptr, sW, af, tid, lr, lg, acc);

    // ---- LayerNorm epilogue
    float g8[8], be8[8];
    #pragma unroll
    for (int ct = 0; ct < 8; ++ct) {
        g8[ct] = gamma[ct * 16 + lr];
        be8[ct] = beta[ct * 16 + lr];
    }
    #pragma unroll
    for (int j = 0; j < 4; ++j) {
        float s1 = 0.f, s2 = 0.f;
        #pragma unroll
        for (int ct = 0; ct < 8; ++ct) {
            float v = acc[ct][j];
            s1 += v; s2 += v * v;
        }
        #pragma unroll
        for (int m = 8; m >= 1; m >>= 1) {
            s1 += __shfl_xor(s1, m);
            s2 += __shfl_xor(s2, m);
        }
        float mu = s1 * (1.f / 128.f);
        float var = s2 * (1.f / 128.f) - mu * mu;
        float rs = rsqrtf(var + 1e-5f);
        int gr = R0 + lg * 4 + j;
        if (act && gr < N_NODES) {
            #pragma unroll
            for (int ct = 0; ct < 8; ++ct)
                out[(size_t)gr * OUT_C + ct * 16 + lr] =
                    (acc[ct][j] - mu) * rs * g8[ct] + be8[ct];
        }
    }
}

extern "C" void kernel_launch(void* const* d_in, const int* in_sizes, int n_in,
                              void* d_out, int out_size, void* d_ws, size_t ws_size,
                              hipStream_t stream)
{
    const float* x       = (const float*)d_in[0];
    const int*   edge    = (const int*)d_in[1];
    const float* message = (const float*)d_in[2];
    const float* W1      = (const float*)d_in[3];
    const float* b1      = (const float*)d_in[4];
    const float* W2      = (const float*)d_in[5];
    const float* b2      = (const float*)d_in[6];
    const float* W3      = (const float*)d_in[7];
    const float* gamma   = (const float*)d_in[8];
    const float* beta    = (const float*)d_in[9];
    float* out  = (float*)d_out;

    // ---- workspace layout (~103 MB, proven-safe range) ----
    char* ws = (char*)d_ws;
    int*   deg     = (int*)(ws);                            //    200,000 B
    int*   cursor  = (int*)(ws + 200000);                   //    200,000 B
    int*   offsets = (int*)(ws + 400000);                   //    200,016 B (N+1)
    int*   bsum    = (int*)(ws + 600016);                   //        196 B
    unsigned short* Wt1 = (unsigned short*)(ws + 600224);   //     49,152 B
    unsigned short* Wt2 = (unsigned short*)(ws + 649376);   //     32,768 B
    unsigned short* Wt3 = (unsigned short*)(ws + 682144);   //     32,768 B
    unsigned int* pbuf  = (unsigned int*)(ws + 714912);     // 102,400,000 B (16-aligned)

    init_kernel<<<224, 256, 0, stream>>>((int4*)deg, W1, W2, W3, Wt1, Wt2, Wt3);

    int qblocks = (N_EDGES / 4 + 255) / 256;   // 782
    hist_kernel<<<qblocks, 256, 0, stream>>>(edge, deg);
    scan_a_kernel<<<SCAN_NB, 1024, 0, stream>>>(deg, offsets, bsum);
    scan_bc_kernel<<<SCAN_NB, 1024, 0, stream>>>(offsets, cursor, bsum);

    permute_kernel<<<N_EDGES * 16 / 256, 256, 0, stream>>>(edge, message, cursor, pbuf);

    mlp_mfma_kernel<<<(N_NODES + 63) / 64, 256, 0, stream>>>(
        x, offsets, (const u32x4*)pbuf, Wt1, b1, Wt2, b2, Wt3, gamma, beta, out);
}

// Round 14
// 157.919 us; speedup vs baseline: 1.6853x; 1.6853x over previous
//
#include <hip/hip_runtime.h>

#define N_NODES 50000
#define N_EDGES 800000
#define IN_C 128
#define MSG_C 64
#define OUT_C 128
#define SCAN_NB 49   // ceil(50000/1024)

typedef __attribute__((ext_vector_type(8))) short short8v;  // 8 bf16 (4 VGPRs)
typedef __attribute__((ext_vector_type(4))) float f32x4;
typedef __attribute__((ext_vector_type(2))) unsigned int u32x2;
typedef __attribute__((ext_vector_type(4))) unsigned int u32x4;

__device__ __forceinline__ unsigned short f2bf(float f) {
    union { float f; unsigned int u; } v; v.f = f;
    unsigned int r = (v.u + 0x7FFFu + ((v.u >> 16) & 1u)) >> 16;
    return (unsigned short)r;
}
__device__ __forceinline__ float bflo(unsigned u) {
    union { unsigned u; float f; } v; v.u = u << 16; return v.f;
}
__device__ __forceinline__ float bfhi(unsigned u) {
    union { unsigned u; float f; } v; v.u = u & 0xFFFF0000u; return v.f;
}

// ---------------------------------------------------------------------------
// init: zero deg (12500 int4) + transpose/convert weights to bf16 Wt[n][k]
// ---------------------------------------------------------------------------
__global__ __launch_bounds__(256) void init_kernel(
    int4* __restrict__ deg4,
    const float* __restrict__ W1, const float* __restrict__ W2,
    const float* __restrict__ W3, unsigned short* __restrict__ Wt1,
    unsigned short* __restrict__ Wt2, unsigned short* __restrict__ Wt3)
{
    int idx = blockIdx.x * 256 + threadIdx.x;
    if (idx < 12500) deg4[idx] = make_int4(0, 0, 0, 0);
    if (idx < 24576) {
        int k = idx >> 7, n = idx & 127;
        Wt1[n * 192 + k] = f2bf(W1[idx]);
    } else if (idx < 40960) {
        int t = idx - 24576;
        int k = t >> 7, n = t & 127;
        Wt2[n * 128 + k] = f2bf(W2[t]);
    } else if (idx < 57344) {
        int t = idx - 40960;
        int k = t >> 7, n = t & 127;
        Wt3[n * 128 + k] = f2bf(W3[t]);
    }
}

// ---------------------------------------------------------------------------
// CSR offsets: histogram -> scan_a -> scan_bc (seeds cursor)
// ---------------------------------------------------------------------------
__global__ __launch_bounds__(256) void hist_kernel(const int* __restrict__ edge_index,
                                                   int* __restrict__ deg)
{
    int i = blockIdx.x * 256 + threadIdx.x;
    if (i >= N_EDGES / 4) return;
    int4 d4 = *reinterpret_cast<const int4*>(edge_index + N_EDGES + i * 4);
    atomicAdd(&deg[d4.x], 1);
    atomicAdd(&deg[d4.y], 1);
    atomicAdd(&deg[d4.z], 1);
    atomicAdd(&deg[d4.w], 1);
}

__global__ __launch_bounds__(1024) void scan_a_kernel(const int* __restrict__ deg,
                                                      int* __restrict__ offsets,
                                                      int* __restrict__ bsum)
{
    __shared__ int wsum[16];
    const int tid = threadIdx.x, lane = tid & 63, wid = tid >> 6;
    int i = blockIdx.x * 1024 + tid;
    int v = (i < N_NODES) ? deg[i] : 0;
    int s = v;
    #pragma unroll
    for (int d = 1; d < 64; d <<= 1) {
        int t = __shfl_up(s, d);
        if (lane >= d) s += t;
    }
    if (lane == 63) wsum[wid] = s;
    __syncthreads();
    if (wid == 0 && lane < 16) {
        int ws = wsum[lane];
        int ss = ws;
        #pragma unroll
        for (int d = 1; d < 16; d <<= 1) {
            int t = __shfl_up(ss, d);
            if (lane >= d) ss += t;
        }
        wsum[lane] = ss - ws;   // exclusive wave offset
    }
    __syncthreads();
    if (i < N_NODES) offsets[i] = s - v + wsum[wid];
    if (tid == 1023) bsum[blockIdx.x] = wsum[15] + s;
}

// every block redundantly scans the 49 block sums; finalizes offsets + cursor
__global__ __launch_bounds__(1024) void scan_bc_kernel(int* __restrict__ offsets,
                                                       int* __restrict__ cursor,
                                                       const int* __restrict__ bsum)
{
    __shared__ int bpre_s, btot_s;
    const int tid = threadIdx.x;
    if (tid < 64) {
        int v = (tid < SCAN_NB) ? bsum[tid] : 0;
        int s = v;
        #pragma unroll
        for (int d = 1; d < 64; d <<= 1) {
            int t = __shfl_up(s, d);
            if (tid >= d) s += t;
        }
        if (tid == (int)blockIdx.x) bpre_s = s - v;   // exclusive prefix of my block
        if (tid == SCAN_NB - 1) btot_s = s;           // grand total
    }
    __syncthreads();
    int i = blockIdx.x * 1024 + tid;
    if (i < N_NODES) {
        int o = offsets[i] + bpre_s;
        offsets[i] = o;
        cursor[i] = o;
    }
    if (blockIdx.x == 0 && tid == 0) offsets[N_NODES] = btot_s;  // == N_EDGES
}

// ---------------------------------------------------------------------------
// permute: stream messages in order (coalesced 256 B reads, NT), convert to
// bf16, write each row to its CSR slot as ONE aligned 128 B line — CACHED
// store (NOT nontemporal): pbuf is 102 MB < 256 MB L3, so random writes are
// absorbed at cache BW instead of random-granule HBM cost. [round-13 counter
// evidence: NT stores forced 126 MB HBM WRITE at ~1.8 TB/s effective]
// ---------------------------------------------------------------------------
__global__ __launch_bounds__(256) void permute_kernel(
    const int* __restrict__ edge_index, const float* __restrict__ message,
    int* __restrict__ cursor, unsigned int* __restrict__ pbuf)
{
    int t = blockIdx.x * 256 + threadIdx.x;
    int e = t >> 4;
    if (e >= N_EDGES) return;
    int lane = threadIdx.x & 63;
    int s = lane & 15;
    int dest = edge_index[N_EDGES + e];
    int pos = 0;
    if (s == 0) pos = atomicAdd(&cursor[dest], 1);
    pos = __shfl(pos, lane & 48);          // broadcast within the 16-lane group
    f32x4 v = __builtin_nontemporal_load(
        reinterpret_cast<const f32x4*>(message + (long)e * MSG_C + s * 4));
    u32x2 p;
    p.x = (unsigned)f2bf(v.x) | ((unsigned)f2bf(v.y) << 16);
    p.y = (unsigned)f2bf(v.z) | ((unsigned)f2bf(v.w) << 16);
    *reinterpret_cast<u32x2*>(pbuf + (long)pos * 32 + s * 2) = p;   // cached
}

// ---------------------------------------------------------------------------
// segsum: rows for node n are contiguous in pbuf; streaming wave-sum.
// CACHED loads — pbuf lines are L3-dirty-resident from permute.
// ---------------------------------------------------------------------------
__global__ __launch_bounds__(256) void segsum_kernel(const int* __restrict__ offsets,
                                                     const u32x4* __restrict__ pbuf4,
                                                     unsigned int* __restrict__ aggr_u32)
{
    const int wid = threadIdx.x >> 6;
    const int lane = threadIdx.x & 63;
    int n = blockIdx.x * 4 + wid;
    if (n >= N_NODES) return;
    int s0 = offsets[n], e0 = offsets[n + 1];
    long base = (long)s0 * 8;
    int cnt = (e0 - s0) * 8;
    float a0 = 0.f, a1 = 0.f, a2 = 0.f, a3 = 0.f,
          a4 = 0.f, a5 = 0.f, a6 = 0.f, a7 = 0.f;
    for (int k = lane; k < cnt; k += 64) {
        u32x4 u = pbuf4[base + k];         // cached (L3-resident)
        a0 += bflo(u.x); a1 += bfhi(u.x);
        a2 += bflo(u.y); a3 += bfhi(u.y);
        a4 += bflo(u.z); a5 += bfhi(u.z);
        a6 += bflo(u.w); a7 += bfhi(u.w);
    }
    #pragma unroll
    for (int m = 8; m <= 32; m <<= 1) {
        a0 += __shfl_xor(a0, m); a1 += __shfl_xor(a1, m);
        a2 += __shfl_xor(a2, m); a3 += __shfl_xor(a3, m);
        a4 += __shfl_xor(a4, m); a5 += __shfl_xor(a5, m);
        a6 += __shfl_xor(a6, m); a7 += __shfl_xor(a7, m);
    }
    if (lane < 8) {
        u32x4 p;
        p.x = (unsigned)f2bf(a0) | ((unsigned)f2bf(a1) << 16);
        p.y = (unsigned)f2bf(a2) | ((unsigned)f2bf(a3) << 16);
        p.z = (unsigned)f2bf(a4) | ((unsigned)f2bf(a5) << 16);
        p.w = (unsigned)f2bf(a6) | ((unsigned)f2bf(a7) << 16);
        *reinterpret_cast<u32x4*>(aggr_u32 + (long)n * 32 + lane * 4) = p;
    }
}

// ---------------------------------------------------------------------------
// MFMA MLP + LayerNorm (round-11 version): weights staged in LDS,
// double-buffered 64-k chunks; 79.9 KB LDS -> 2 blocks/CU.
// A-frag: row = lane&15, k = (lane>>4)*8 + j ; C/D: col = lane&15,
// row = (lane>>4)*4 + j  [m89-verified]
// ---------------------------------------------------------------------------
__device__ __forceinline__ void stage_load(const unsigned short* __restrict__ Wt,
                                           int KW, int k0, int tid, u32x4 r[4])
{
    const u32x4* src = reinterpret_cast<const u32x4*>(
        Wt + (size_t)(tid >> 1) * KW + k0 + (tid & 1) * 32);
    r[0] = src[0]; r[1] = src[1]; r[2] = src[2]; r[3] = src[3];
}

__device__ __forceinline__ void stage_write(unsigned short* __restrict__ sw,
                                            int tid, const u32x4 r[4])
{
    u32x4* dst = reinterpret_cast<u32x4*>(sw + (tid >> 1) * 72 + (tid & 1) * 32);
    dst[0] = r[0]; dst[1] = r[1]; dst[2] = r[2]; dst[3] = r[3];
}

template<int KW, bool BIAS>
__device__ __forceinline__ void gemm_layer_lds(
    const unsigned short* __restrict__ Wt, const float* __restrict__ bias,
    unsigned short* __restrict__ sW,      // [2][128][72] flat
    const short8v* af, int tid, int lr, int lg, f32x4 acc[8])
{
    constexpr int NCH = KW / 64;
    #pragma unroll
    for (int ct = 0; ct < 8; ++ct) {
        float bv = BIAS ? bias[ct * 16 + lr] : 0.f;
        acc[ct] = (f32x4){bv, bv, bv, bv};
    }
    u32x4 r[4];
    stage_load(Wt, KW, 0, tid, r);
    stage_write(sW, tid, r);
    __syncthreads();
    #pragma unroll
    for (int c = 0; c < NCH; ++c) {
        if (c + 1 < NCH) stage_load(Wt, KW, (c + 1) * 64, tid, r);   // issue early
        const unsigned short* swc = sW + (c & 1) * (128 * 72);
        #pragma unroll
        for (int k2 = 0; k2 < 2; ++k2) {
            #pragma unroll
            for (int ct = 0; ct < 8; ++ct) {
                short8v b = *reinterpret_cast<const short8v*>(
                    swc + (ct * 16 + lr) * 72 + k2 * 32 + lg * 8);
                acc[ct] = __builtin_amdgcn_mfma_f32_16x16x32_bf16(
                    af[c * 2 + k2], b, acc[ct], 0, 0, 0);
            }
        }
        if (c + 1 < NCH) stage_write(sW + ((c + 1) & 1) * (128 * 72), tid, r);
        __syncthreads();
    }
}

__device__ __forceinline__ void store_h_leaky(unsigned short* __restrict__ H,
                                              int lr, int lg, const f32x4 acc[8])
{
    #pragma unroll
    for (int ct = 0; ct < 8; ++ct)
        #pragma unroll
        for (int j = 0; j < 4; ++j) {
            float v = acc[ct][j];
            v = v > 0.f ? v : 0.2f * v;
            H[(lg * 4 + j) * 136 + ct * 16 + lr] = f2bf(v);
        }
}

__global__ __launch_bounds__(256, 2) void mlp_mfma_kernel(
    const float* __restrict__ x, const unsigned short* __restrict__ aggr_bf,
    const unsigned short* __restrict__ Wt1, const float* __restrict__ b1,
    const unsigned short* __restrict__ Wt2, const float* __restrict__ b2,
    const unsigned short* __restrict__ Wt3, const float* __restrict__ gamma,
    const float* __restrict__ beta, float* __restrict__ out)
{
    __shared__ __align__(16) unsigned short sA0[4][16][200];  // 25600 B
    __shared__ __align__(16) unsigned short sH[4][16][136];   // 17408 B
    __shared__ __align__(16) unsigned short sW[2 * 128 * 72]; // 36864 B
    // total 79,872 B -> 2 blocks/CU

    const int tid = threadIdx.x;
    const int w = tid >> 6, l = tid & 63;
    const int lr = l & 15, lg = l >> 4;
    const int R0 = blockIdx.x * 64 + w * 16;
    const bool act = (R0 < N_NODES);   // inactive waves still hit all barriers

    // ---- stage x (f32 -> bf16) into sA0[:, 0:128]
    #pragma unroll
    for (int i = 0; i < 4; ++i) {
        int r = lg + i * 4;
        int c0 = lr * 8;
        int gr = R0 + r;
        float4 v0 = {}, v1 = {};
        if (gr < N_NODES) {
            const float4* xp = reinterpret_cast<const float4*>(x + (size_t)gr * IN_C + c0);
            v0 = xp[0]; v1 = xp[1];
        }
        uint4 p;
        p.x = (unsigned)f2bf(v0.x) | ((unsigned)f2bf(v0.y) << 16);
        p.y = (unsigned)f2bf(v0.z) | ((unsigned)f2bf(v0.w) << 16);
        p.z = (unsigned)f2bf(v1.x) | ((unsigned)f2bf(v1.y) << 16);
        p.w = (unsigned)f2bf(v1.z) | ((unsigned)f2bf(v1.w) << 16);
        *reinterpret_cast<uint4*>(&sA0[w][r][c0]) = p;
    }
    // ---- stage aggr (already bf16) into sA0[:, 128:192]
    #pragma unroll
    for (int i = 0; i < 2; ++i) {
        int r = (l >> 3) + i * 8;
        int c0 = (l & 7) * 8;
        int gr = R0 + r;
        uint4 a4 = {};
        if (gr < N_NODES)
            a4 = *reinterpret_cast<const uint4*>(aggr_bf + (size_t)gr * MSG_C + c0);
        *reinterpret_cast<uint4*>(&sA0[w][r][IN_C + c0]) = a4;
    }

    f32x4 acc[8];
    short8v af[6];

    // layer 1: K=192
    #pragma unroll
    for (int ks = 0; ks < 6; ++ks)
        af[ks] = *reinterpret_cast<const short8v*>(&sA0[w][lr][ks * 32 + lg * 8]);
    gemm_layer_lds<192, true>(Wt1, b1, sW, af, tid, lr, lg, acc);
    store_h_leaky(&sH[w][0][0], lr, lg, acc);

    // layer 2: K=128
    #pragma unroll
    for (int ks = 0; ks < 4; ++ks)
        af[ks] = *reinterpret_cast<const short8v*>(&sH[w][lr][ks * 32 + lg * 8]);
    gemm_layer_lds<128, true>(Wt2, b2, sW, af, tid, lr, lg, acc);
    store_h_leaky(&sH[w][0][0], lr, lg, acc);   // h2 overwrites h1 (a-frags in regs)

    // layer 3: K=128, no bias
    #pragma unroll
    for (int ks = 0; ks < 4; ++ks)
        af[ks] = *reinterpret_cast<const short8v*>(&sH[w][lr][ks * 32 + lg * 8]);
    gemm_layer_lds<128, false>(Wt3, nullptr, sW, af, tid, lr, lg, acc);

    // ---- LayerNorm epilogue
    float g8[8], be8[8];
    #pragma unroll
    for (int ct = 0; ct < 8; ++ct) {
        g8[ct] = gamma[ct * 16 + lr];
        be8[ct] = beta[ct * 16 + lr];
    }
    #pragma unroll
    for (int j = 0; j < 4; ++j) {
        float s1 = 0.f, s2 = 0.f;
        #pragma unroll
        for (int ct = 0; ct < 8; ++ct) {
            float v = acc[ct][j];
            s1 += v; s2 += v * v;
        }
        #pragma unroll
        for (int m = 8; m >= 1; m >>= 1) {
            s1 += __shfl_xor(s1, m);
            s2 += __shfl_xor(s2, m);
        }
        float mu = s1 * (1.f / 128.f);
        float var = s2 * (1.f / 128.f) - mu * mu;
        float rs = rsqrtf(var + 1e-5f);
        int gr = R0 + lg * 4 + j;
        if (act && gr < N_NODES) {
            #pragma unroll
            for (int ct = 0; ct < 8; ++ct)
                out[(size_t)gr * OUT_C + ct * 16 + lr] =
                    (acc[ct][j] - mu) * rs * g8[ct] + be8[ct];
        }
    }
}

extern "C" void kernel_launch(void* const* d_in, const int* in_sizes, int n_in,
                              void* d_out, int out_size, void* d_ws, size_t ws_size,
                              hipStream_t stream)
{
    const float* x       = (const float*)d_in[0];
    const int*   edge    = (const int*)d_in[1];
    const float* message = (const float*)d_in[2];
    const float* W1      = (const float*)d_in[3];
    const float* b1      = (const float*)d_in[4];
    const float* W2      = (const float*)d_in[5];
    const float* b2      = (const float*)d_in[6];
    const float* W3      = (const float*)d_in[7];
    const float* gamma   = (const float*)d_in[8];
    const float* beta    = (const float*)d_in[9];
    float* out  = (float*)d_out;

    // ---- workspace layout (~110 MB, proven-safe) ----
    char* ws = (char*)d_ws;
    unsigned short* aggr_bf = (unsigned short*)(ws);        //  6,400,000 B
    int*   deg     = (int*)(ws + 6400000);                  //    200,000 B
    int*   cursor  = (int*)(ws + 6600000);                  //    200,000 B
    int*   offsets = (int*)(ws + 6800000);                  //    200,016 B (N+1)
    int*   bsum    = (int*)(ws + 7000016);                  //        196 B
    unsigned short* Wt1 = (unsigned short*)(ws + 7000224);  //     49,152 B
    unsigned short* Wt2 = (unsigned short*)(ws + 7049376);  //     32,768 B
    unsigned short* Wt3 = (unsigned short*)(ws + 7082144);  //     32,768 B
    unsigned int* pbuf  = (unsigned int*)(ws + 7115008);    // 102,400,000 B (16-aligned)

    init_kernel<<<224, 256, 0, stream>>>((int4*)deg, W1, W2, W3, Wt1, Wt2, Wt3);

    int qblocks = (N_EDGES / 4 + 255) / 256;   // 782
    hist_kernel<<<qblocks, 256, 0, stream>>>(edge, deg);
    scan_a_kernel<<<SCAN_NB, 1024, 0, stream>>>(deg, offsets, bsum);
    scan_bc_kernel<<<SCAN_NB, 1024, 0, stream>>>(offsets, cursor, bsum);

    permute_kernel<<<N_EDGES * 16 / 256, 256, 0, stream>>>(edge, message, cursor, pbuf);

    segsum_kernel<<<(N_NODES + 3) / 4, 256, 0, stream>>>(
        offsets, (const u32x4*)pbuf, (unsigned int*)aggr_bf);

    mlp_mfma_kernel<<<(N_NODES + 63) / 64, 256, 0, stream>>>(
        x, aggr_bf, Wt1, b1, Wt2, b2, Wt3, gamma, beta, out);
}